// Round 1
// baseline (562.485 us; speedup 1.0000x reference)
//
#include <hip/hip_runtime.h>
#include <math.h>

// Problem: B=256, K=16, SZ=512, D=8
// dists[b,k] = max_s ( sum_{t,d} x[b,t+s,d]*c[k,t,d] ) / (||x_b|| * k),  s in [-511,511]
//   k=0 -> denom<1e-9 -> dist=0.  labels[b] = first k attaining max dists.
// Output layout (float32): out[0..255]=labels, out[256..4351]=dists[b][k].

#define NB 256
#define NK 16
#define NS 512
#define ND 8
#define JP 1536   // zero-padded plane length: [0,511)=0, [511,1023)=x, [1023,1536)=0
#define TC 32     // t-chunk size for staged c

__global__ __launch_bounds__(256, 2) void dists_kernel(
    const float* __restrict__ x, const float* __restrict__ c, float* __restrict__ out)
{
    __shared__ __align__(16) float xs[ND][JP];      // 49152 B
    __shared__ __align__(16) float ct[8][ND][TC];   //  8192 B
    __shared__ float red[4][4];
    __shared__ float redn[4];
    __shared__ float s_norm;

    const int tid   = threadIdx.x;
    const int b     = blockIdx.x;
    const int kbase = blockIdx.y * 8;

    // ---- zero-fill padding regions of xs ----
    #pragma unroll
    for (int d = 0; d < ND; ++d) {
        for (int j = tid; j < 511; j += 256)        xs[d][j] = 0.f;
        for (int j = 1023 + tid; j < JP; j += 256)  xs[d][j] = 0.f;
    }

    // ---- load x[b] (transposed into planes) + sum of squares ----
    const float4* x4 = (const float4*)(x + (size_t)b * (NS * ND));
    float ss = 0.f;
    #pragma unroll
    for (int i = 0; i < 4; ++i) {
        int g = tid + i * 256;            // float4 index in [0,1024)
        float4 v = x4[g];
        int t  = g >> 1;
        int dh = (g & 1) * 4;
        xs[dh + 0][511 + t] = v.x;
        xs[dh + 1][511 + t] = v.y;
        xs[dh + 2][511 + t] = v.z;
        xs[dh + 3][511 + t] = v.w;
        ss += v.x * v.x + v.y * v.y + v.z * v.z + v.w * v.w;
    }
    #pragma unroll
    for (int off = 32; off; off >>= 1) ss += __shfl_down(ss, off, 64);
    if ((tid & 63) == 0) redn[tid >> 6] = ss;
    __syncthreads();
    if (tid == 0) s_norm = sqrtf(redn[0] + redn[1] + redn[2] + redn[3]);

    // thread -> (k-quad, lag group)
    const int kgrp = tid >> 7;        // 0: k kbase..kbase+3, 1: kbase+4..kbase+7
    const int lt   = tid & 127;       // lag group: window1 = 4*lt+l, window2 = 512+4*lt+l

    float acc1[4][4], acc2[4][4];
    #pragma unroll
    for (int a = 0; a < 4; ++a)
        #pragma unroll
        for (int l = 0; l < 4; ++l) { acc1[a][l] = 0.f; acc2[a][l] = 0.f; }

    const float4* c4 = (const float4*)c;

    for (int t0 = 0; t0 < NS; t0 += TC) {
        __syncthreads();
        // ---- stage c chunk: 8 k * 8 d * TC floats = 512 float4 ----
        #pragma unroll
        for (int i = 0; i < 2; ++i) {
            int g = tid + i * 256;        // [0,512)
            int kidx = g >> 6;            // 64 float4 per k
            int r = g & 63;
            int t = r >> 1;
            int dh = (r & 1) * 4;
            float4 v = c4[(size_t)(kbase + kidx) * (NS * ND / 4) + (size_t)(t0 + t) * 2 + (r & 1)];
            ct[kidx][dh + 0][t] = v.x;
            ct[kidx][dh + 1][t] = v.y;
            ct[kidx][dh + 2][t] = v.z;
            ct[kidx][dh + 3][t] = v.w;
        }
        __syncthreads();

        for (int d = 0; d < ND; ++d) {
            const float4* q1 = (const float4*)&xs[d][t0 + 4 * lt];
            const float4* q2 = (const float4*)&xs[d][t0 + 4 * lt + 512];
            float4 A1 = q1[0], A2 = q2[0];
            #pragma unroll
            for (int u = 0; u < TC / 4; ++u) {
                float4 B1 = q1[u + 1];
                float4 B2 = q2[u + 1];
                float4 cb0 = *(const float4*)&ct[kgrp * 4 + 0][d][4 * u];
                float4 cb1 = *(const float4*)&ct[kgrp * 4 + 1][d][4 * u];
                float4 cb2 = *(const float4*)&ct[kgrp * 4 + 2][d][4 * u];
                float4 cb3 = *(const float4*)&ct[kgrp * 4 + 3][d][4 * u];
                float w1[8] = {A1.x, A1.y, A1.z, A1.w, B1.x, B1.y, B1.z, B1.w};
                float w2[8] = {A2.x, A2.y, A2.z, A2.w, B2.x, B2.y, B2.z, B2.w};
                float cvs[4][4] = {{cb0.x, cb0.y, cb0.z, cb0.w},
                                   {cb1.x, cb1.y, cb1.z, cb1.w},
                                   {cb2.x, cb2.y, cb2.z, cb2.w},
                                   {cb3.x, cb3.y, cb3.z, cb3.w}};
                #pragma unroll
                for (int tt = 0; tt < 4; ++tt) {
                    #pragma unroll
                    for (int a = 0; a < 4; ++a) {
                        float cvv = cvs[a][tt];
                        #pragma unroll
                        for (int l = 0; l < 4; ++l) {
                            acc1[a][l] = fmaf(w1[tt + l], cvv, acc1[a][l]);
                            acc2[a][l] = fmaf(w2[tt + l], cvv, acc2[a][l]);
                        }
                    }
                }
                A1 = B1; A2 = B2;
            }
        }
    }

    // ---- per-thread max over lags (exclude phantom lag sidx=1023) ----
    float m[4];
    #pragma unroll
    for (int a = 0; a < 4; ++a) {
        float mm = acc1[a][0];
        #pragma unroll
        for (int l = 1; l < 4; ++l) mm = fmaxf(mm, acc1[a][l]);
        #pragma unroll
        for (int l = 0; l < 4; ++l) {
            if (!(lt == 127 && l == 3)) mm = fmaxf(mm, acc2[a][l]);
        }
        m[a] = mm;
    }

    __syncthreads();   // protect red[] reuse
    #pragma unroll
    for (int a = 0; a < 4; ++a) {
        float mm = m[a];
        #pragma unroll
        for (int off = 32; off; off >>= 1) mm = fmaxf(mm, __shfl_down(mm, off, 64));
        if ((tid & 63) == 0) red[tid >> 6][a] = mm;
    }
    __syncthreads();

    if (tid < 8) {
        int kq = tid & 3;
        int kg = tid >> 2;                 // which k-quad
        float mm = fmaxf(red[kg * 2][kq], red[kg * 2 + 1][kq]);
        int kglob = kbase + tid;
        float denom = s_norm * (float)kglob;
        float dist = (denom < 1e-9f) ? 0.f : mm / denom;
        out[NB + b * NK + kglob] = dist;
    }
}

__global__ void labels_kernel(float* __restrict__ out)
{
    int b = threadIdx.x;
    const float* d = out + NB + b * NK;
    float best = d[0];
    int lab = 0;
    #pragma unroll
    for (int k = 1; k < NK; ++k) {
        float v = d[k];
        if (v > best) { best = v; lab = k; }
    }
    out[b] = (float)lab;
}

extern "C" void kernel_launch(void* const* d_in, const int* in_sizes, int n_in,
                              void* d_out, int out_size, void* d_ws, size_t ws_size,
                              hipStream_t stream) {
    const float* x = (const float*)d_in[0];
    const float* c = (const float*)d_in[1];
    float* out = (float*)d_out;
    dists_kernel<<<dim3(NB, 2), 256, 0, stream>>>(x, c, out);
    labels_kernel<<<1, 256, 0, stream>>>(out);
}

// Round 2
// 79.484 us; speedup vs baseline: 7.0767x; 7.0767x over previous
//
#include <hip/hip_runtime.h>
#include <math.h>

// KShape dists via bf16 MFMA. B=256, K=16, SZ=512, D=8.
// corr[b,i,k] = sum_{t,d} xpad[b][(i+t)*8+d] * c[k][t*8+d],  i in [0,1022] (lag s=i-511)
// dists[b,k] = max_i corr / (||x_b|| * k); k=0 -> 0. labels = first argmax.
// out: [0..255]=labels(float), [256..4351]=dists.

#define NB 256
#define NK 16
#define NS 512
#define ND 8

typedef __bf16 bf16x8 __attribute__((ext_vector_type(8)));
typedef float floatx4 __attribute__((ext_vector_type(4)));

// ---- pack centers into B-fragment order ----
// Bpk[kc*64 + L][0..8) = bf16( c[n = L&15][ (kc*4 + (L>>4))*8 + j ] )  j=0..7
__global__ void pack_kernel(const float* __restrict__ c, __bf16* __restrict__ bpk)
{
    int kc = blockIdx.x;      // 0..127 chunk of 32 contraction elems
    int L  = threadIdx.x;     // 0..63
    int n = L & 15, quad = L >> 4;
    const float4* src = (const float4*)(c + ((size_t)n * NS + (size_t)(kc * 4 + quad)) * ND);
    float4 a = src[0], b = src[1];
    bf16x8 v;
    v[0] = (__bf16)a.x; v[1] = (__bf16)a.y; v[2] = (__bf16)a.z; v[3] = (__bf16)a.w;
    v[4] = (__bf16)b.x; v[5] = (__bf16)b.y; v[6] = (__bf16)b.z; v[7] = (__bf16)b.w;
    *(bf16x8*)(bpk + ((size_t)kc * 64 + L) * 8) = v;
}

// ---- main: one block = (b, quarter q of the 1024 lag rows) ----
__global__ __launch_bounds__(256, 4) void dists_mfma(
    const float* __restrict__ x, const __bf16* __restrict__ bpk, float* __restrict__ wsf)
{
    __shared__ __align__(16) __bf16 xq[800 * 8];   // 12.5 KB: padded-x band, bf16
    __shared__ float wred[4][16];

    const int tid = threadIdx.x;
    const int b   = blockIdx.x;
    const int q   = blockIdx.y;
    const int m0  = q * 256;

    // stage band rows jj: global padded index j = m0+jj; x support is j in [511,1023)
    for (int jj = tid; jj < 800; jj += 256) {
        int j = m0 + jj;
        bf16x8 v;
        if (j >= 511 && j < 1023) {
            const float4* p = (const float4*)(x + ((size_t)b * NS + (size_t)(j - 511)) * ND);
            float4 a = p[0], bb = p[1];
            v[0] = (__bf16)a.x;  v[1] = (__bf16)a.y;  v[2] = (__bf16)a.z;  v[3] = (__bf16)a.w;
            v[4] = (__bf16)bb.x; v[5] = (__bf16)bb.y; v[6] = (__bf16)bb.z; v[7] = (__bf16)bb.w;
        } else {
            #pragma unroll
            for (int e = 0; e < 8; ++e) v[e] = (__bf16)0.0f;
        }
        *(bf16x8*)(xq + (size_t)jj * 8) = v;
    }
    __syncthreads();

    const int L    = tid & 63;
    const int w    = tid >> 6;     // wave id: handles block-local tiles 4w..4w+3
    const int m    = L & 15;       // A row within tile / D col (center id)
    const int quad = L >> 4;

    // A-frag for (rt, kc): 16B at xq + 8*(64w + 16rt + 4kc + m + quad)
    const __bf16* gb = xq + 8 * (64 * w + m + quad);
    const bf16x8* Bp = (const bf16x8*)bpk;

    // ring: Q[i] = frag at rel row 4*(kc0 + i); frag(rt,kc) = Q[(kc + 4rt)&15]
    bf16x8 Q[16];
    #pragma unroll
    for (int i = 0; i < 16; ++i) Q[i] = *(const bf16x8*)(gb + 8 * (4 * i));

    floatx4 acc[4] = {};

    bf16x8 bcur = Bp[L];
    for (int kc0 = 0; kc0 < 128; kc0 += 16) {
        #pragma unroll
        for (int s = 0; s < 16; ++s) {
            const int kc = kc0 + s;
            bf16x8 bnxt = Bp[(size_t)((kc + 1) & 127) * 64 + L];
            bf16x8 qn = *(const bf16x8*)(gb + 8 * (4 * kc + 64));  // max row 782 < 800
            acc[0] = __builtin_amdgcn_mfma_f32_16x16x32_bf16(Q[(s + 0)  & 15], bcur, acc[0], 0, 0, 0);
            acc[1] = __builtin_amdgcn_mfma_f32_16x16x32_bf16(Q[(s + 4)  & 15], bcur, acc[1], 0, 0, 0);
            acc[2] = __builtin_amdgcn_mfma_f32_16x16x32_bf16(Q[(s + 8)  & 15], bcur, acc[2], 0, 0, 0);
            acc[3] = __builtin_amdgcn_mfma_f32_16x16x32_bf16(Q[(s + 12) & 15], bcur, acc[3], 0, 0, 0);
            Q[s] = qn;
            bcur = bnxt;
        }
    }

    // D layout: col = lane&15 (center), row-in-tile = quad*4 + e.
    // global lag = 256q + 64w + 16rt + 4quad + e; phantom row 1023 excluded.
    float vmax = -INFINITY;
    #pragma unroll
    for (int r = 0; r < 4; ++r) {
        #pragma unroll
        for (int e = 0; e < 4; ++e) {
            bool phantom = (q == 3) & (w == 3) & (r == 3) & (quad == 3) & (e == 3);
            vmax = fmaxf(vmax, phantom ? -INFINITY : acc[r][e]);
        }
    }
    vmax = fmaxf(vmax, __shfl_xor(vmax, 16));
    vmax = fmaxf(vmax, __shfl_xor(vmax, 32));
    if (quad == 0) wred[w][m] = vmax;
    __syncthreads();
    if (tid < 16) {
        float mm = fmaxf(fmaxf(wred[0][tid], wred[1][tid]),
                         fmaxf(wred[2][tid], wred[3][tid]));
        wsf[((size_t)b * 4 + q) * 16 + tid] = mm;
    }
}

// ---- finalize: norm, scale, dists, labels ----
__global__ void finalize(const float* __restrict__ x, const float* __restrict__ wsf,
                         float* __restrict__ out)
{
    __shared__ float redn[4];
    __shared__ float dd[16];
    const int b = blockIdx.x, tid = threadIdx.x;
    const float4* x4 = (const float4*)(x + (size_t)b * (NS * ND));
    float ss = 0.f;
    #pragma unroll
    for (int i = 0; i < 4; ++i) {
        float4 v = x4[tid + 256 * i];
        ss += v.x * v.x + v.y * v.y + v.z * v.z + v.w * v.w;
    }
    #pragma unroll
    for (int off = 32; off; off >>= 1) ss += __shfl_down(ss, off);
    if ((tid & 63) == 0) redn[tid >> 6] = ss;
    __syncthreads();
    float nrm = sqrtf(redn[0] + redn[1] + redn[2] + redn[3]);
    if (tid < 16) {
        const float* wp = wsf + (size_t)b * 64 + tid;
        float mm = fmaxf(fmaxf(wp[0], wp[16]), fmaxf(wp[32], wp[48]));
        float denom = nrm * (float)tid;
        float d = (denom < 1e-9f) ? 0.f : mm / denom;
        dd[tid] = d;
        out[NB + b * NK + tid] = d;
    }
    __syncthreads();
    if (tid == 0) {
        float best = dd[0]; int lab = 0;
        #pragma unroll
        for (int k = 1; k < NK; ++k) if (dd[k] > best) { best = dd[k]; lab = k; }
        out[b] = (float)lab;
    }
}

extern "C" void kernel_launch(void* const* d_in, const int* in_sizes, int n_in,
                              void* d_out, int out_size, void* d_ws, size_t ws_size,
                              hipStream_t stream) {
    const float* x = (const float*)d_in[0];
    const float* c = (const float*)d_in[1];
    float* out = (float*)d_out;
    float* wsf = (float*)d_ws;                          // 256*4*16 floats = 64 KB
    __bf16* bpk = (__bf16*)((char*)d_ws + 65536);       // 128 chunks * 1 KB = 128 KB

    pack_kernel<<<128, 64, 0, stream>>>(c, bpk);
    dists_mfma<<<dim3(NB, 4), 256, 0, stream>>>(x, bpk, wsf);
    finalize<<<NB, 256, 0, stream>>>(x, wsf, out);
}